// Round 15
// baseline (415.081 us; speedup 1.0000x reference)
//
#include <hip/hip_runtime.h>
#include <hip/hip_bf16.h>

#define IN_DIM 128
#define HID_DIM 256
#define OUT_DIM 40
#define SCAN_CHUNK 2048

typedef __attribute__((ext_vector_type(8))) __bf16 bf16x8;
typedef __attribute__((ext_vector_type(4))) float f32x4;

__device__ inline ushort f2bf(float f) {
    uint u = __builtin_bit_cast(uint, f);
    u = (u + 0x7fff + ((u >> 16) & 1)) >> 16;
    return (ushort)u;
}
__device__ inline float bfl(uint u) { return __builtin_bit_cast(float, u << 16); }
__device__ inline float bfh(uint u) { return __builtin_bit_cast(float, u & 0xffff0000u); }

// ---------------- input conversion ----------------
__global__ __launch_bounds__(256) void cvt_x(const float* __restrict__ in,
                                             ushort* __restrict__ out, int n4) {
    int i = blockIdx.x * 256 + threadIdx.x;
    if (i < n4) {
        float4 v = ((const float4*)in)[i];
        uint2 o;
        o.x = (uint)f2bf(v.x) | ((uint)f2bf(v.y) << 16);
        o.y = (uint)f2bf(v.z) | ((uint)f2bf(v.w) << 16);
        ((uint2*)out)[i] = o;
    }
}

__global__ __launch_bounds__(256) void cvt_weights(
    const float* __restrict__ Wl1, const float* __restrict__ Wr1,
    const float* __restrict__ Wl2, const float* __restrict__ Wr2,
    const float* __restrict__ Wl3, const float* __restrict__ Wr3,
    ushort* __restrict__ o1l, ushort* __restrict__ o1r,
    ushort* __restrict__ o2l, ushort* __restrict__ o2r,
    ushort* __restrict__ o3l, ushort* __restrict__ o3r) {
    int idx = blockIdx.x * 256 + threadIdx.x;
    if (idx < 32768) {
        o1l[idx] = f2bf(Wl1[idx]);
        o1r[idx] = f2bf(Wr1[idx]);
        return;
    }
    idx -= 32768;
    if (idx < 65536) {
        o2l[idx] = f2bf(Wl2[idx]);
        o2r[idx] = f2bf(Wr2[idx]);
        return;
    }
    idx -= 65536;
    if (idx < 48 * 256) {
        int row = idx >> 8;
        int col = idx & 255;
        ushort vl = 0, vr = 0;
        if (row < OUT_DIM) {
            vl = f2bf(Wl3[row * 256 + col]);
            vr = f2bf(Wr3[row * 256 + col]);
        }
        o3l[idx] = vl;
        o3r[idx] = vr;
    }
}

// ---------------- CSR build ----------------
__global__ __launch_bounds__(256) void hist_kernel(const int* __restrict__ dst,
                                                   int* __restrict__ cnt, int E) {
    int e = blockIdx.x * 256 + threadIdx.x;
    if (e < E) atomicAdd(&cnt[dst[e]], 1);
}

__global__ __launch_bounds__(256) void scan_pass1(const int* __restrict__ cnt,
                                                  int* __restrict__ bsum, int N) {
    __shared__ int red[256];
    const int base = blockIdx.x * SCAN_CHUNK;
    int s = 0;
    for (int i = threadIdx.x; i < SCAN_CHUNK; i += 256) {
        int idx = base + i;
        if (idx < N) s += cnt[idx];
    }
    red[threadIdx.x] = s;
    __syncthreads();
    for (int o = 128; o > 0; o >>= 1) {
        if (threadIdx.x < o) red[threadIdx.x] += red[threadIdx.x + o];
        __syncthreads();
    }
    if (threadIdx.x == 0) bsum[blockIdx.x] = red[0];
}

__global__ __launch_bounds__(256) void scan_pass3(const int* __restrict__ cnt,
                                                  const int* __restrict__ bsum,
                                                  int* __restrict__ rowptr,
                                                  int* __restrict__ cursor,
                                                  float* __restrict__ inv,
                                                  int N, int E, int SB) {
    __shared__ int ls[256];
    __shared__ int boff;
    if (threadIdx.x == 0) {
        int r = 0;
        for (int i = 0; i < blockIdx.x; ++i) r += bsum[i];
        boff = r;
    }
    const int tbase = blockIdx.x * SCAN_CHUNK + threadIdx.x * 8;
    int c[8];
    int s = 0;
#pragma unroll
    for (int j = 0; j < 8; ++j) {
        int idx = tbase + j;
        c[j] = (idx < N) ? cnt[idx] : 0;
        s += c[j];
    }
    ls[threadIdx.x] = s;
    __syncthreads();
    for (int o = 1; o < 256; o <<= 1) {
        int u = (threadIdx.x >= o) ? ls[threadIdx.x - o] : 0;
        __syncthreads();
        ls[threadIdx.x] += u;
        __syncthreads();
    }
    int run = boff + ls[threadIdx.x] - s;
#pragma unroll
    for (int j = 0; j < 8; ++j) {
        int idx = tbase + j;
        if (idx < N) {
            rowptr[idx] = run;
            cursor[idx] = run;
            inv[idx] = 1.0f / fmaxf((float)c[j], 1.0f);
            run += c[j];
        }
    }
    if (blockIdx.x == 0 && threadIdx.x == 0) rowptr[N] = E;
}

__global__ __launch_bounds__(256) void fill_kernel(const int* __restrict__ src,
                                                   const int* __restrict__ dst,
                                                   int* __restrict__ cursor,
                                                   int* __restrict__ srcs, int E) {
    int e = blockIdx.x * 256 + threadIdx.x;
    if (e < E) {
        int pos = atomicAdd(&cursor[dst[e]], 1);
        srcs[pos] = src[e];
    }
}

// ---------------- FUSED gather-mean + SAGE GEMM ----------------
// Block owns 64 output rows. Phase G: each wave gather-means 16 rows of
// `feat` (scaled by inv) into LDS As[64][K+8] (bf16). Phase M: 4 col-tiles
// of 64 over O=256; per tile, Wl then Wr staged into Ws; mean-phase A-frags
// come from LDS (zero global A traffic), self-phase A-frags from global
// (R13 pattern). Eliminates the M intermediate entirely.
template <int K, int MINW>
__global__ __launch_bounds__(256, MINW) void sage_fused(
    const ushort* __restrict__ feat, const int* __restrict__ rowptr,
    const int* __restrict__ srcs, const float* __restrict__ inv,
    const ushort* __restrict__ Wl, const float* __restrict__ bias,
    const ushort* __restrict__ Wr, ushort* __restrict__ outp, int N) {
    constexpr int KP = K + 8;
    constexpr int NK = K / 32;
    constexpr int V = K / 64;  // gather cols per lane (2 or 4)
    __shared__ __align__(16) ushort As[64 * KP];
    __shared__ __align__(16) ushort Ws[64 * KP];

    const int tid = threadIdx.x;
    const int wave = tid >> 6;
    const int lane = tid & 63;
    const int ln = lane & 15;
    const int quad = lane >> 4;
    const int bm0 = blockIdx.x * 64;

    // ---- phase G: gather means for this wave's 16 rows into As ----
    for (int i = 0; i < 16; ++i) {
        const int n = bm0 + wave * 16 + i;
        if (n >= N) break;
        const int beg = rowptr[n];
        const int end = rowptr[n + 1];
        const int col = lane * V;
        float a0 = 0.f, a1 = 0.f, a2 = 0.f, a3 = 0.f;
        int e = beg;
        if constexpr (V == 4) {
            for (; e + 7 < end; e += 8) {
                uint2 q[8];
#pragma unroll
                for (int j = 0; j < 8; ++j)
                    q[j] = *(const uint2*)&feat[(long long)srcs[e + j] * K + col];
#pragma unroll
                for (int j = 0; j < 8; ++j) {
                    a0 += bfl(q[j].x); a1 += bfh(q[j].x);
                    a2 += bfl(q[j].y); a3 += bfh(q[j].y);
                }
            }
            for (; e + 3 < end; e += 4) {
                uint2 q[4];
#pragma unroll
                for (int j = 0; j < 4; ++j)
                    q[j] = *(const uint2*)&feat[(long long)srcs[e + j] * K + col];
#pragma unroll
                for (int j = 0; j < 4; ++j) {
                    a0 += bfl(q[j].x); a1 += bfh(q[j].x);
                    a2 += bfl(q[j].y); a3 += bfh(q[j].y);
                }
            }
            for (; e < end; ++e) {
                uint2 q0 = *(const uint2*)&feat[(long long)srcs[e] * K + col];
                a0 += bfl(q0.x); a1 += bfh(q0.x); a2 += bfl(q0.y); a3 += bfh(q0.y);
            }
            const float sc = inv[n];
            uint2 o;
            o.x = (uint)f2bf(a0 * sc) | ((uint)f2bf(a1 * sc) << 16);
            o.y = (uint)f2bf(a2 * sc) | ((uint)f2bf(a3 * sc) << 16);
            *(uint2*)&As[(wave * 16 + i) * KP + col] = o;
        } else {
            for (; e + 7 < end; e += 8) {
                uint q[8];
#pragma unroll
                for (int j = 0; j < 8; ++j)
                    q[j] = *(const uint*)&feat[(long long)srcs[e + j] * K + col];
#pragma unroll
                for (int j = 0; j < 8; ++j) {
                    a0 += bfl(q[j]); a1 += bfh(q[j]);
                }
            }
            for (; e + 3 < end; e += 4) {
                uint q[4];
#pragma unroll
                for (int j = 0; j < 4; ++j)
                    q[j] = *(const uint*)&feat[(long long)srcs[e + j] * K + col];
#pragma unroll
                for (int j = 0; j < 4; ++j) {
                    a0 += bfl(q[j]); a1 += bfh(q[j]);
                }
            }
            for (; e < end; ++e) {
                uint q0 = *(const uint*)&feat[(long long)srcs[e] * K + col];
                a0 += bfl(q0); a1 += bfh(q0);
            }
            const float sc = inv[n];
            uint o = (uint)f2bf(a0 * sc) | ((uint)f2bf(a1 * sc) << 16);
            *(uint*)&As[(wave * 16 + i) * KP + col] = o;
        }
    }

    const int arow = min(bm0 + wave * 16 + ln, N - 1);  // self rows (clamped)

    // ---- phase M: 4 col-tiles of 64 over O=256 ----
    f32x4 acc[4];
    for (int ct = 0; ct < 4; ++ct) {
#pragma unroll
        for (int ph = 0; ph < 2; ++ph) {
            const ushort* __restrict__ W = ph ? Wr : Wl;
            __syncthreads();  // Ws reuse guard (also As-ready on first iter)
#pragma unroll
            for (int i = tid; i < 64 * (K / 8); i += 256) {
                int row = i / (K / 8);
                int c8 = (i % (K / 8)) * 8;
                *(ulonglong2*)&Ws[row * KP + c8] =
                    *(const ulonglong2*)&W[(long long)(ct * 64 + row) * K + c8];
            }
            __syncthreads();
            if (ph == 0) {
#pragma unroll
                for (int c4 = 0; c4 < 4; ++c4) acc[c4] = (f32x4){0.f, 0.f, 0.f, 0.f};
            }
#pragma unroll
            for (int kk = 0; kk < NK; ++kk) {
                bf16x8 a;
                if (ph == 0)
                    a = *(const bf16x8*)&As[(wave * 16 + ln) * KP + kk * 32 + quad * 8];
                else
                    a = *(const bf16x8*)&feat[(long long)arow * K + kk * 32 + quad * 8];
#pragma unroll
                for (int c4 = 0; c4 < 4; ++c4) {
                    bf16x8 b = *(const bf16x8*)&Ws[(c4 * 16 + ln) * KP + kk * 32 + quad * 8];
                    acc[c4] = __builtin_amdgcn_mfma_f32_16x16x32_bf16(a, b, acc[c4], 0, 0, 0);
                }
            }
        }
        // epilogue for this 64-col tile: bias + relu + bf16 store
        int rbase = bm0 + wave * 16 + quad * 4;
#pragma unroll
        for (int c4 = 0; c4 < 4; ++c4) {
            int col = ct * 64 + c4 * 16 + ln;
            float bv = bias[col];
#pragma unroll
            for (int r = 0; r < 4; ++r) {
                int row = rbase + r;
                if (row < N)
                    outp[(long long)row * HID_DIM + col] = f2bf(fmaxf(acc[c4][r] + bv, 0.f));
            }
        }
    }
}

// ---------------- layer-3 pre-aggregation GEMM: P = A@Wl^T (bf16), S = A@Wr^T (fp32) ----------------
template <int K>
__global__ __launch_bounds__(256, 3) void sage_gemm_pre(const ushort* __restrict__ A0,
                                                        const ushort* __restrict__ Wl,
                                                        const ushort* __restrict__ Wr,
                                                        ushort* __restrict__ P,
                                                        float* __restrict__ S, int N, int O) {
    constexpr int KP = 2 * K + 8;
    constexpr int NK = K / 32;  // 8
    __shared__ __align__(16) ushort Ws[48 * KP];  // 49 KB

    const int tid = threadIdx.x;
    const int wave = tid >> 6;
    const int lane = tid & 63;
    const int ln = lane & 15;
    const int quad = lane >> 4;
    const int bm0 = blockIdx.x * 64;

    const int arow = min(bm0 + wave * 16 + ln, N - 1);

#pragma unroll
    for (int i = tid; i < 48 * (K / 8); i += 256) {
        int row = i / (K / 8);
        int c8 = (i % (K / 8)) * 8;
        *(ulonglong2*)&Ws[row * KP + c8] =
            *(const ulonglong2*)&Wl[(long long)row * K + c8];
        *(ulonglong2*)&Ws[row * KP + K + c8] =
            *(const ulonglong2*)&Wr[(long long)row * K + c8];
    }
    __syncthreads();

#pragma unroll
    for (int phase = 0; phase < 2; ++phase) {
        f32x4 acc[3] = {};
#pragma unroll
        for (int kk = 0; kk < NK; ++kk) {
            bf16x8 a = *(const bf16x8*)&A0[(long long)arow * K + kk * 32 + quad * 8];
#pragma unroll
            for (int ct = 0; ct < 3; ++ct) {
                bf16x8 b = *(const bf16x8*)&Ws[(ct * 16 + ln) * KP + phase * K + kk * 32 + quad * 8];
                acc[ct] = __builtin_amdgcn_mfma_f32_16x16x32_bf16(a, b, acc[ct], 0, 0, 0);
            }
        }
        int rbase = bm0 + wave * 16 + quad * 4;
#pragma unroll
        for (int ct = 0; ct < 3; ++ct) {
            int col = ct * 16 + ln;
            if (col >= O) continue;
#pragma unroll
            for (int r = 0; r < 4; ++r) {
                int row = rbase + r;
                if (row >= N) continue;
                if (phase == 0)
                    P[(long long)row * O + col] = f2bf(acc[ct][r]);
                else
                    S[(long long)row * O + col] = acc[ct][r];
            }
        }
    }
}

// ---------------- fused mean-agg(D=40) + self + bias + log_softmax ----------------
__global__ __launch_bounds__(256) void agg_bias_lsm(const ushort* __restrict__ P,
                                                    const float* __restrict__ S,
                                                    const float* __restrict__ bias,
                                                    const int* __restrict__ rowptr,
                                                    const int* __restrict__ srcs,
                                                    const float* __restrict__ inv,
                                                    float* __restrict__ out, int N) {
    const int wave = threadIdx.x >> 6;
    const int lane = threadIdx.x & 63;
    const int n = blockIdx.x * 4 + wave;
    if (n >= N) return;
    const int beg = rowptr[n];
    const int end = rowptr[n + 1];
    const bool act = lane < OUT_DIM;
    const int cidx = act ? lane : 0;

    float acc = 0.f;
    int e = beg;
    for (; e + 3 < end; e += 4) {
        int s0 = srcs[e], s1 = srcs[e + 1], s2 = srcs[e + 2], s3 = srcs[e + 3];
        float v0 = __builtin_bit_cast(float, (uint)P[(long long)s0 * OUT_DIM + cidx] << 16);
        float v1 = __builtin_bit_cast(float, (uint)P[(long long)s1 * OUT_DIM + cidx] << 16);
        float v2 = __builtin_bit_cast(float, (uint)P[(long long)s2 * OUT_DIM + cidx] << 16);
        float v3 = __builtin_bit_cast(float, (uint)P[(long long)s3 * OUT_DIM + cidx] << 16);
        acc += (v0 + v1) + (v2 + v3);
    }
    for (; e < end; ++e)
        acc += __builtin_bit_cast(float, (uint)P[(long long)srcs[e] * OUT_DIM + cidx] << 16);

    float v = act ? (acc * inv[n] + S[(long long)n * OUT_DIM + lane] + bias[lane]) : -INFINITY;
    float m = v;
#pragma unroll
    for (int o = 32; o > 0; o >>= 1) m = fmaxf(m, __shfl_xor(m, o, 64));
    float ex = act ? expf(v - m) : 0.f;
    float sm = ex;
#pragma unroll
    for (int o = 32; o > 0; o >>= 1) sm += __shfl_xor(sm, o, 64);
    float ls = logf(sm);
    if (act) out[(long long)n * OUT_DIM + lane] = v - m - ls;
}

extern "C" void kernel_launch(void* const* d_in, const int* in_sizes, int n_in,
                              void* d_out, int out_size, void* d_ws, size_t ws_size,
                              hipStream_t stream) {
    const float* x   = (const float*)d_in[0];
    const int*   ei  = (const int*)d_in[1];
    const float* Wl1 = (const float*)d_in[2];
    const float* bl1 = (const float*)d_in[3];
    const float* Wr1 = (const float*)d_in[4];
    const float* Wl2 = (const float*)d_in[5];
    const float* bl2 = (const float*)d_in[6];
    const float* Wr2 = (const float*)d_in[7];
    const float* Wl3 = (const float*)d_in[8];
    const float* bl3 = (const float*)d_in[9];
    const float* Wr3 = (const float*)d_in[10];
    float* out = (float*)d_out;

    const int N = in_sizes[0] / IN_DIM;  // 50000
    const int E = in_sizes[1] / 2;       // 600000
    const int* src = ei;
    const int* dst = ei + E;

    // ---- workspace layout ----
    char* w = (char*)d_ws;
    size_t off = 0;
    auto alloc = [&](size_t bytes) {
        void* p = w + off;
        off = (off + bytes + 255) & ~(size_t)255;
        return p;
    };
    ushort* xb   = (ushort*)alloc((size_t)N * IN_DIM * 2);
    ushort* H1   = (ushort*)alloc((size_t)N * HID_DIM * 2);
    ushort* H2   = (ushort*)alloc((size_t)N * HID_DIM * 2);
    ushort* P3   = (ushort*)alloc((size_t)N * OUT_DIM * 2);
    float*  S3   = (float*)alloc((size_t)N * OUT_DIM * 4);
    float*  inv  = (float*)alloc((size_t)N * 4);
    int*    cnt  = (int*)alloc((size_t)N * 4);
    int*    rowptr = (int*)alloc((size_t)(N + 1) * 4);
    int*    cursor = (int*)alloc((size_t)N * 4);
    int*    srcs = (int*)alloc((size_t)E * 4);
    int*    bsum = (int*)alloc(256 * 4);
    ushort* Wl1b = (ushort*)alloc(256 * 128 * 2);
    ushort* Wr1b = (ushort*)alloc(256 * 128 * 2);
    ushort* Wl2b = (ushort*)alloc(256 * 256 * 2);
    ushort* Wr2b = (ushort*)alloc(256 * 256 * 2);
    ushort* Wl3b = (ushort*)alloc(48 * 256 * 2);
    ushort* Wr3b = (ushort*)alloc(48 * 256 * 2);

    // ---- conversions ----
    cvt_x<<<(N * IN_DIM / 4 + 255) / 256, 256, 0, stream>>>(x, xb, N * IN_DIM / 4);
    cvt_weights<<<(32768 + 65536 + 48 * 256 + 255) / 256, 256, 0, stream>>>(
        Wl1, Wr1, Wl2, Wr2, Wl3, Wr3, Wl1b, Wr1b, Wl2b, Wr2b, Wl3b, Wr3b);

    // ---- CSR build ----
    const int SB = (N + SCAN_CHUNK - 1) / SCAN_CHUNK;  // 25
    hipMemsetAsync(cnt, 0, (size_t)N * sizeof(int), stream);
    hist_kernel<<<(E + 255) / 256, 256, 0, stream>>>(dst, cnt, E);
    scan_pass1<<<SB, 256, 0, stream>>>(cnt, bsum, N);
    scan_pass3<<<SB, 256, 0, stream>>>(cnt, bsum, rowptr, cursor, inv, N, E, SB);
    fill_kernel<<<(E + 255) / 256, 256, 0, stream>>>(src, dst, cursor, srcs, E);

    const int gb = (N + 63) / 64;  // 782
    const int gg = (N + 3) / 4;

    // ---- layer 1 (fused gather+GEMM): K=128 -> 256, relu ----
    sage_fused<IN_DIM, 4><<<gb, 256, 0, stream>>>(
        xb, rowptr, srcs, inv, Wl1b, bl1, Wr1b, H1, N);

    // ---- layer 2 (fused gather+GEMM): K=256 -> 256, relu ----
    sage_fused<HID_DIM, 2><<<gb, 256, 0, stream>>>(
        H1, rowptr, srcs, inv, Wl2b, bl2, Wr2b, H2, N);

    // ---- layer 3 (GEMM-first): P3 = H2@Wl3^T, S3 = H2@Wr3^T, then fused agg+lsm ----
    sage_gemm_pre<HID_DIM><<<gb, 256, 0, stream>>>(
        H2, Wl3b, Wr3b, P3, S3, N, OUT_DIM);
    agg_bias_lsm<<<gg, 256, 0, stream>>>(P3, S3, bl3, rowptr, srcs, inv, out, N);
}

// Round 16
// 353.040 us; speedup vs baseline: 1.1757x; 1.1757x over previous
//
#include <hip/hip_runtime.h>
#include <hip/hip_bf16.h>

#define IN_DIM 128
#define HID_DIM 256
#define OUT_DIM 40
#define SCAN_CHUNK 2048

typedef __attribute__((ext_vector_type(8))) __bf16 bf16x8;
typedef __attribute__((ext_vector_type(4))) float f32x4;

__device__ inline ushort f2bf(float f) {
    uint u = __builtin_bit_cast(uint, f);
    u = (u + 0x7fff + ((u >> 16) & 1)) >> 16;
    return (ushort)u;
}
__device__ inline float bfl(uint u) { return __builtin_bit_cast(float, u << 16); }
__device__ inline float bfh(uint u) { return __builtin_bit_cast(float, u & 0xffff0000u); }

// ---------------- fused prep: cvt_x + cvt_weights + hist (independent jobs) ----------------
// segment 0: blocks [0, XB)            -> x fp32 -> bf16 (float4/lane)
// segment 1: blocks [XB, XB+WB)        -> 3 weight pairs fp32 -> bf16 (L3 zero-padded to 48 rows)
// segment 2: blocks [XB+WB, XB+WB+HB)  -> histogram of dst
__global__ __launch_bounds__(256) void prep_kernel(
    const float* __restrict__ x, ushort* __restrict__ xb, int n4, int XB,
    const float* __restrict__ Wl1, const float* __restrict__ Wr1,
    const float* __restrict__ Wl2, const float* __restrict__ Wr2,
    const float* __restrict__ Wl3, const float* __restrict__ Wr3,
    ushort* __restrict__ o1l, ushort* __restrict__ o1r,
    ushort* __restrict__ o2l, ushort* __restrict__ o2r,
    ushort* __restrict__ o3l, ushort* __restrict__ o3r, int WB,
    const int* __restrict__ dst, int* __restrict__ cnt, int E) {
    int b = blockIdx.x;
    if (b < XB) {
        int i = b * 256 + threadIdx.x;
        if (i < n4) {
            float4 v = ((const float4*)x)[i];
            uint2 o;
            o.x = (uint)f2bf(v.x) | ((uint)f2bf(v.y) << 16);
            o.y = (uint)f2bf(v.z) | ((uint)f2bf(v.w) << 16);
            ((uint2*)xb)[i] = o;
        }
        return;
    }
    b -= XB;
    if (b < WB) {
        int idx = b * 256 + threadIdx.x;
        if (idx < 32768) {
            o1l[idx] = f2bf(Wl1[idx]);
            o1r[idx] = f2bf(Wr1[idx]);
            return;
        }
        idx -= 32768;
        if (idx < 65536) {
            o2l[idx] = f2bf(Wl2[idx]);
            o2r[idx] = f2bf(Wr2[idx]);
            return;
        }
        idx -= 65536;
        if (idx < 48 * 256) {
            int row = idx >> 8;
            int col = idx & 255;
            ushort vl = 0, vr = 0;
            if (row < OUT_DIM) {
                vl = f2bf(Wl3[row * 256 + col]);
                vr = f2bf(Wr3[row * 256 + col]);
            }
            o3l[idx] = vl;
            o3r[idx] = vr;
        }
        return;
    }
    b -= WB;
    int e = b * 256 + threadIdx.x;
    if (e < E) atomicAdd(&cnt[dst[e]], 1);
}

// ---------------- CSR scan ----------------
__global__ __launch_bounds__(256) void scan_pass1(const int* __restrict__ cnt,
                                                  int* __restrict__ bsum, int N) {
    __shared__ int red[256];
    const int base = blockIdx.x * SCAN_CHUNK;
    int s = 0;
    for (int i = threadIdx.x; i < SCAN_CHUNK; i += 256) {
        int idx = base + i;
        if (idx < N) s += cnt[idx];
    }
    red[threadIdx.x] = s;
    __syncthreads();
    for (int o = 128; o > 0; o >>= 1) {
        if (threadIdx.x < o) red[threadIdx.x] += red[threadIdx.x + o];
        __syncthreads();
    }
    if (threadIdx.x == 0) bsum[blockIdx.x] = red[0];
}

__global__ __launch_bounds__(256) void scan_pass3(const int* __restrict__ cnt,
                                                  const int* __restrict__ bsum,
                                                  int* __restrict__ rowptr,
                                                  int* __restrict__ cursor,
                                                  float* __restrict__ inv,
                                                  int N, int E, int SB) {
    __shared__ int ls[256];
    __shared__ int boff;
    if (threadIdx.x == 0) {
        int r = 0;
        for (int i = 0; i < blockIdx.x; ++i) r += bsum[i];
        boff = r;
    }
    const int tbase = blockIdx.x * SCAN_CHUNK + threadIdx.x * 8;
    int c[8];
    int s = 0;
#pragma unroll
    for (int j = 0; j < 8; ++j) {
        int idx = tbase + j;
        c[j] = (idx < N) ? cnt[idx] : 0;
        s += c[j];
    }
    ls[threadIdx.x] = s;
    __syncthreads();
    for (int o = 1; o < 256; o <<= 1) {
        int u = (threadIdx.x >= o) ? ls[threadIdx.x - o] : 0;
        __syncthreads();
        ls[threadIdx.x] += u;
        __syncthreads();
    }
    int run = boff + ls[threadIdx.x] - s;
#pragma unroll
    for (int j = 0; j < 8; ++j) {
        int idx = tbase + j;
        if (idx < N) {
            rowptr[idx] = run;
            cursor[idx] = run;
            inv[idx] = 1.0f / fmaxf((float)c[j], 1.0f);
            run += c[j];
        }
    }
    if (blockIdx.x == 0 && threadIdx.x == 0) rowptr[N] = E;
}

__global__ __launch_bounds__(256) void fill_kernel(const int* __restrict__ src,
                                                   const int* __restrict__ dst,
                                                   int* __restrict__ cursor,
                                                   int* __restrict__ srcs, int E) {
    int e = blockIdx.x * 256 + threadIdx.x;
    if (e < E) {
        int pos = atomicAdd(&cursor[dst[e]], 1);
        srcs[pos] = src[e];
    }
}

// ---------------- gather mean (bf16, fp32 accumulate, 8-wide ILP) ----------------
template <int D>
__global__ __launch_bounds__(256) void gather_mean_bf(const ushort* __restrict__ feat,
                                                      const int* __restrict__ rowptr,
                                                      const int* __restrict__ srcs,
                                                      const float* __restrict__ inv,
                                                      ushort* __restrict__ out, int N) {
    constexpr int V = D / 64;  // bf16 per lane: 2 or 4
    const int wave = threadIdx.x >> 6;
    const int lane = threadIdx.x & 63;
    const int n = blockIdx.x * 4 + wave;
    if (n >= N) return;
    const int beg = rowptr[n];
    const int end = rowptr[n + 1];
    const int col = lane * V;
    float a0 = 0.f, a1 = 0.f, a2 = 0.f, a3 = 0.f;
    int e = beg;
    if constexpr (V == 4) {
        for (; e + 7 < end; e += 8) {
            uint2 q[8];
#pragma unroll
            for (int j = 0; j < 8; ++j)
                q[j] = *(const uint2*)&feat[(long long)srcs[e + j] * D + col];
#pragma unroll
            for (int j = 0; j < 8; ++j) {
                a0 += bfl(q[j].x); a1 += bfh(q[j].x);
                a2 += bfl(q[j].y); a3 += bfh(q[j].y);
            }
        }
        for (; e + 3 < end; e += 4) {
            uint2 q[4];
#pragma unroll
            for (int j = 0; j < 4; ++j)
                q[j] = *(const uint2*)&feat[(long long)srcs[e + j] * D + col];
#pragma unroll
            for (int j = 0; j < 4; ++j) {
                a0 += bfl(q[j].x); a1 += bfh(q[j].x);
                a2 += bfl(q[j].y); a3 += bfh(q[j].y);
            }
        }
        for (; e < end; ++e) {
            uint2 q0 = *(const uint2*)&feat[(long long)srcs[e] * D + col];
            a0 += bfl(q0.x); a1 += bfh(q0.x); a2 += bfl(q0.y); a3 += bfh(q0.y);
        }
        const float sc = inv[n];
        uint2 o;
        o.x = (uint)f2bf(a0 * sc) | ((uint)f2bf(a1 * sc) << 16);
        o.y = (uint)f2bf(a2 * sc) | ((uint)f2bf(a3 * sc) << 16);
        *(uint2*)&out[(long long)n * D + col] = o;
    } else {
        for (; e + 7 < end; e += 8) {
            uint q[8];
#pragma unroll
            for (int j = 0; j < 8; ++j)
                q[j] = *(const uint*)&feat[(long long)srcs[e + j] * D + col];
#pragma unroll
            for (int j = 0; j < 8; ++j) {
                a0 += bfl(q[j]); a1 += bfh(q[j]);
            }
        }
        for (; e + 3 < end; e += 4) {
            uint q[4];
#pragma unroll
            for (int j = 0; j < 4; ++j)
                q[j] = *(const uint*)&feat[(long long)srcs[e + j] * D + col];
#pragma unroll
            for (int j = 0; j < 4; ++j) {
                a0 += bfl(q[j]); a1 += bfh(q[j]);
            }
        }
        for (; e < end; ++e) {
            uint q0 = *(const uint*)&feat[(long long)srcs[e] * D + col];
            a0 += bfl(q0); a1 += bfh(q0);
        }
        const float sc = inv[n];
        uint o = (uint)f2bf(a0 * sc) | ((uint)f2bf(a1 * sc) << 16);
        *(uint*)&out[(long long)n * D + col] = o;
    }
}

// ---------------- MFMA SAGE GEMM (R13 structure — measured best) ----------------
template <int K, bool RELU, bool OUTBF>
__global__ __launch_bounds__(256, 3) void sage_gemm_mfma(const ushort* __restrict__ Amean,
                                                         const ushort* __restrict__ Aself,
                                                         const ushort* __restrict__ Wl,
                                                         const float* __restrict__ bias,
                                                         const ushort* __restrict__ Wr,
                                                         void* __restrict__ outv, int N, int O) {
    constexpr int KP = K + 8;   // padded LDS row (conflict-free ds_read_b128)
    constexpr int NK = K / 32;  // k-steps per phase
    __shared__ __align__(16) ushort Ws[64 * KP];

    const int tid = threadIdx.x;
    const int wave = tid >> 6;
    const int lane = tid & 63;
    const int ln = lane & 15;
    const int quad = lane >> 4;
    const int bm0 = blockIdx.y * 128;  // row-block (slow axis)
    const int bn0 = blockIdx.x * 64;   // col-block (fast axis)

    int arow[2];
#pragma unroll
    for (int rt = 0; rt < 2; ++rt) {
        int r = bm0 + wave * 32 + rt * 16 + ln;
        arow[rt] = min(r, N - 1);
    }

    f32x4 acc[2][4] = {};

    for (int phase = 0; phase < 2; ++phase) {
        const ushort* __restrict__ A = phase ? Aself : Amean;
        const ushort* __restrict__ W = phase ? Wr : Wl;

        __syncthreads();  // Ws reuse guard
#pragma unroll
        for (int i = tid; i < 64 * (K / 8); i += 256) {
            int row = i / (K / 8);
            int c8 = (i % (K / 8)) * 8;
            *(ulonglong2*)&Ws[row * KP + c8] =
                *(const ulonglong2*)&W[(long long)(bn0 + row) * K + c8];
        }
        __syncthreads();

        bf16x8 areg[NK][2];
#pragma unroll
        for (int kk = 0; kk < NK; ++kk)
#pragma unroll
            for (int rt = 0; rt < 2; ++rt)
                areg[kk][rt] = *(const bf16x8*)&A[(long long)arow[rt] * K + kk * 32 + quad * 8];

#pragma unroll
        for (int kk = 0; kk < NK; ++kk) {
#pragma unroll
            for (int ct = 0; ct < 4; ++ct) {
                bf16x8 b = *(const bf16x8*)&Ws[(ct * 16 + ln) * KP + kk * 32 + quad * 8];
#pragma unroll
                for (int rt = 0; rt < 2; ++rt)
                    acc[rt][ct] = __builtin_amdgcn_mfma_f32_16x16x32_bf16(areg[kk][rt], b, acc[rt][ct], 0, 0, 0);
            }
        }
    }

#pragma unroll
    for (int rt = 0; rt < 2; ++rt) {
        int rbase = bm0 + wave * 32 + rt * 16 + quad * 4;
#pragma unroll
        for (int ct = 0; ct < 4; ++ct) {
            int col = bn0 + ct * 16 + ln;
            if (col >= O) continue;
            float bv = bias[col];
#pragma unroll
            for (int r = 0; r < 4; ++r) {
                int row = rbase + r;
                if (row >= N) continue;
                float v = acc[rt][ct][r] + bv;
                if (RELU) v = fmaxf(v, 0.f);
                if (OUTBF)
                    ((ushort*)outv)[(long long)row * O + col] = f2bf(v);
                else
                    ((float*)outv)[(long long)row * O + col] = v;
            }
        }
    }
}

// ---------------- layer-3 pre-aggregation GEMM: P = A@Wl^T (bf16), S = A@Wr^T (fp32) ----------------
template <int K>
__global__ __launch_bounds__(256, 3) void sage_gemm_pre(const ushort* __restrict__ A0,
                                                        const ushort* __restrict__ Wl,
                                                        const ushort* __restrict__ Wr,
                                                        ushort* __restrict__ P,
                                                        float* __restrict__ S, int N, int O) {
    constexpr int KP = 2 * K + 8;
    constexpr int NK = K / 32;  // 8
    __shared__ __align__(16) ushort Ws[48 * KP];  // 49 KB

    const int tid = threadIdx.x;
    const int wave = tid >> 6;
    const int lane = tid & 63;
    const int ln = lane & 15;
    const int quad = lane >> 4;
    const int bm0 = blockIdx.x * 64;

    const int arow = min(bm0 + wave * 16 + ln, N - 1);

#pragma unroll
    for (int i = tid; i < 48 * (K / 8); i += 256) {
        int row = i / (K / 8);
        int c8 = (i % (K / 8)) * 8;
        *(ulonglong2*)&Ws[row * KP + c8] =
            *(const ulonglong2*)&Wl[(long long)row * K + c8];
        *(ulonglong2*)&Ws[row * KP + K + c8] =
            *(const ulonglong2*)&Wr[(long long)row * K + c8];
    }
    __syncthreads();

#pragma unroll
    for (int phase = 0; phase < 2; ++phase) {
        f32x4 acc[3] = {};
#pragma unroll
        for (int kk = 0; kk < NK; ++kk) {
            bf16x8 a = *(const bf16x8*)&A0[(long long)arow * K + kk * 32 + quad * 8];
#pragma unroll
            for (int ct = 0; ct < 3; ++ct) {
                bf16x8 b = *(const bf16x8*)&Ws[(ct * 16 + ln) * KP + phase * K + kk * 32 + quad * 8];
                acc[ct] = __builtin_amdgcn_mfma_f32_16x16x32_bf16(a, b, acc[ct], 0, 0, 0);
            }
        }
        int rbase = bm0 + wave * 16 + quad * 4;
#pragma unroll
        for (int ct = 0; ct < 3; ++ct) {
            int col = ct * 16 + ln;
            if (col >= O) continue;
#pragma unroll
            for (int r = 0; r < 4; ++r) {
                int row = rbase + r;
                if (row >= N) continue;
                if (phase == 0)
                    P[(long long)row * O + col] = f2bf(acc[ct][r]);
                else
                    S[(long long)row * O + col] = acc[ct][r];
            }
        }
    }
}

// ---------------- fused mean-agg(D=40) + self + bias + log_softmax ----------------
__global__ __launch_bounds__(256) void agg_bias_lsm(const ushort* __restrict__ P,
                                                    const float* __restrict__ S,
                                                    const float* __restrict__ bias,
                                                    const int* __restrict__ rowptr,
                                                    const int* __restrict__ srcs,
                                                    const float* __restrict__ inv,
                                                    float* __restrict__ out, int N) {
    const int wave = threadIdx.x >> 6;
    const int lane = threadIdx.x & 63;
    const int n = blockIdx.x * 4 + wave;
    if (n >= N) return;
    const int beg = rowptr[n];
    const int end = rowptr[n + 1];
    const bool act = lane < OUT_DIM;
    const int cidx = act ? lane : 0;

    float acc = 0.f;
    int e = beg;
    for (; e + 3 < end; e += 4) {
        int s0 = srcs[e], s1 = srcs[e + 1], s2 = srcs[e + 2], s3 = srcs[e + 3];
        float v0 = __builtin_bit_cast(float, (uint)P[(long long)s0 * OUT_DIM + cidx] << 16);
        float v1 = __builtin_bit_cast(float, (uint)P[(long long)s1 * OUT_DIM + cidx] << 16);
        float v2 = __builtin_bit_cast(float, (uint)P[(long long)s2 * OUT_DIM + cidx] << 16);
        float v3 = __builtin_bit_cast(float, (uint)P[(long long)s3 * OUT_DIM + cidx] << 16);
        acc += (v0 + v1) + (v2 + v3);
    }
    for (; e < end; ++e)
        acc += __builtin_bit_cast(float, (uint)P[(long long)srcs[e] * OUT_DIM + cidx] << 16);

    float v = act ? (acc * inv[n] + S[(long long)n * OUT_DIM + lane] + bias[lane]) : -INFINITY;
    float m = v;
#pragma unroll
    for (int o = 32; o > 0; o >>= 1) m = fmaxf(m, __shfl_xor(m, o, 64));
    float ex = act ? expf(v - m) : 0.f;
    float sm = ex;
#pragma unroll
    for (int o = 32; o > 0; o >>= 1) sm += __shfl_xor(sm, o, 64);
    float ls = logf(sm);
    if (act) out[(long long)n * OUT_DIM + lane] = v - m - ls;
}

extern "C" void kernel_launch(void* const* d_in, const int* in_sizes, int n_in,
                              void* d_out, int out_size, void* d_ws, size_t ws_size,
                              hipStream_t stream) {
    const float* x   = (const float*)d_in[0];
    const int*   ei  = (const int*)d_in[1];
    const float* Wl1 = (const float*)d_in[2];
    const float* bl1 = (const float*)d_in[3];
    const float* Wr1 = (const float*)d_in[4];
    const float* Wl2 = (const float*)d_in[5];
    const float* bl2 = (const float*)d_in[6];
    const float* Wr2 = (const float*)d_in[7];
    const float* Wl3 = (const float*)d_in[8];
    const float* bl3 = (const float*)d_in[9];
    const float* Wr3 = (const float*)d_in[10];
    float* out = (float*)d_out;

    const int N = in_sizes[0] / IN_DIM;  // 50000
    const int E = in_sizes[1] / 2;       // 600000
    const int* src = ei;
    const int* dst = ei + E;

    // ---- workspace layout ----
    char* w = (char*)d_ws;
    size_t off = 0;
    auto alloc = [&](size_t bytes) {
        void* p = w + off;
        off = (off + bytes + 255) & ~(size_t)255;
        return p;
    };
    ushort* xb   = (ushort*)alloc((size_t)N * IN_DIM * 2);
    ushort* M    = (ushort*)alloc((size_t)N * HID_DIM * 2);
    ushort* H1   = (ushort*)alloc((size_t)N * HID_DIM * 2);
    ushort* H2   = (ushort*)alloc((size_t)N * HID_DIM * 2);
    ushort* P3   = (ushort*)alloc((size_t)N * OUT_DIM * 2);
    float*  S3   = (float*)alloc((size_t)N * OUT_DIM * 4);
    float*  inv  = (float*)alloc((size_t)N * 4);
    int*    cnt  = (int*)alloc((size_t)N * 4);
    int*    rowptr = (int*)alloc((size_t)(N + 1) * 4);
    int*    cursor = (int*)alloc((size_t)N * 4);
    int*    srcs = (int*)alloc((size_t)E * 4);
    int*    bsum = (int*)alloc(256 * 4);
    ushort* Wl1b = (ushort*)alloc(256 * 128 * 2);
    ushort* Wr1b = (ushort*)alloc(256 * 128 * 2);
    ushort* Wl2b = (ushort*)alloc(256 * 256 * 2);
    ushort* Wr2b = (ushort*)alloc(256 * 256 * 2);
    ushort* Wl3b = (ushort*)alloc(48 * 256 * 2);
    ushort* Wr3b = (ushort*)alloc(48 * 256 * 2);

    // ---- prep: cvt_x + cvt_weights + hist in one launch ----
    const int n4 = N * IN_DIM / 4;
    const int XB = (n4 + 255) / 256;
    const int WB = (32768 + 65536 + 48 * 256 + 255) / 256;
    const int HB = (E + 255) / 256;
    hipMemsetAsync(cnt, 0, (size_t)N * sizeof(int), stream);
    prep_kernel<<<XB + WB + HB, 256, 0, stream>>>(
        x, xb, n4, XB,
        Wl1, Wr1, Wl2, Wr2, Wl3, Wr3,
        Wl1b, Wr1b, Wl2b, Wr2b, Wl3b, Wr3b, WB,
        dst, cnt, E);

    // ---- CSR scan + fill ----
    const int SB = (N + SCAN_CHUNK - 1) / SCAN_CHUNK;  // 25
    scan_pass1<<<SB, 256, 0, stream>>>(cnt, bsum, N);
    scan_pass3<<<SB, 256, 0, stream>>>(cnt, bsum, rowptr, cursor, inv, N, E, SB);
    fill_kernel<<<HB, 256, 0, stream>>>(src, dst, cursor, srcs, E);

    const int gm = (N + 127) / 128;  // 391
    const int gg = (N + 3) / 4;

    // ---- layer 1: K=128 -> 256, relu ----
    gather_mean_bf<IN_DIM><<<gg, 256, 0, stream>>>(xb, rowptr, srcs, inv, M, N);
    sage_gemm_mfma<IN_DIM, true, true><<<dim3(4, gm), 256, 0, stream>>>(
        M, xb, Wl1b, bl1, Wr1b, H1, N, HID_DIM);

    // ---- layer 2: K=256 -> 256, relu ----
    gather_mean_bf<HID_DIM><<<gg, 256, 0, stream>>>(H1, rowptr, srcs, inv, M, N);
    sage_gemm_mfma<HID_DIM, true, true><<<dim3(4, gm), 256, 0, stream>>>(
        M, H1, Wl2b, bl2, Wr2b, H2, N, HID_DIM);

    // ---- layer 3 (GEMM-first): P3 = H2@Wl3^T, S3 = H2@Wr3^T, then fused agg+lsm ----
    sage_gemm_pre<HID_DIM><<<(N + 63) / 64, 256, 0, stream>>>(
        H2, Wl3b, Wr3b, P3, S3, N, OUT_DIM);
    agg_bias_lsm<<<gg, 256, 0, stream>>>(P3, S3, bl3, rowptr, srcs, inv, out, N);
}